// Round 4
// baseline (1589.455 us; speedup 1.0000x reference)
//
#include <hip/hip_runtime.h>
#include <hip/hip_bf16.h>
#include <cstdint>

// MultiHeadAttention w/ sparsemax: B=2, S=2048, D=1024, H=16, DK=64
#define S_LEN  2048
#define DMODEL 1024
#define NHEAD  16
#define M_ROWS 4096                       // B*S
#define HEAD_ELEMS (2048u * 64u)          // per (b,h) Q/K/V elems
#define CAP 512                           // per-row candidate list capacity

typedef __attribute__((ext_vector_type(8))) short bf16x8;   // MFMA A/B frag (8 bf16)
typedef __attribute__((ext_vector_type(4))) float f32x4;    // MFMA C/D frag

__device__ __forceinline__ unsigned short f2bf(float f) {
    __hip_bfloat16 h = __float2bfloat16(f);
    return __builtin_bit_cast(unsigned short, h);
}
__device__ __forceinline__ float bf2f(unsigned short u) {
    return __builtin_bit_cast(float, (unsigned)u << 16);
}

__device__ __forceinline__ float wave_sum64(float v) {
    v += __shfl_xor(v, 32, 64); v += __shfl_xor(v, 16, 64);
    v += __shfl_xor(v, 8, 64);  v += __shfl_xor(v, 4, 64);
    v += __shfl_xor(v, 2, 64);  v += __shfl_xor(v, 1, 64);
    return v;
}

// --------------------------------------------------------------- cast fp32->bf16
__global__ __launch_bounds__(256)
void cast_kernel(const float* __restrict__ xq, const float* __restrict__ xk,
                 const float* __restrict__ xv, const float* __restrict__ Wq,
                 const float* __restrict__ Wk, const float* __restrict__ Wv,
                 const float* __restrict__ Wfc, unsigned short* __restrict__ out) {
    const size_t e = ((size_t)blockIdx.x * 256 + threadIdx.x) * 4;
    const size_t M1 = 1u << 20, M4 = 4u << 20;
    const float* src; size_t off;
    if      (e < M4)        { src = xq;  off = e; }
    else if (e < 2 * M4)    { src = xk;  off = e - M4; }
    else if (e < 3 * M4)    { src = xv;  off = e - 2 * M4; }
    else if (e < 13 * M1)   { src = Wq;  off = e - 3 * M4; }
    else if (e < 14 * M1)   { src = Wk;  off = e - 13 * M1; }
    else if (e < 15 * M1)   { src = Wv;  off = e - 14 * M1; }
    else                    { src = Wfc; off = e - 15 * M1; }
    float4 v = *(const float4*)(src + off);
    unsigned int lo = ((unsigned)f2bf(v.y) << 16) | f2bf(v.x);
    unsigned int hi = ((unsigned)f2bf(v.w) << 16) | f2bf(v.z);
    uint2 st = { lo, hi };
    *(uint2*)(out + e) = st;
}

// ------------------------------------------------- qkv: C = A@W^T + b (bf16 MFMA)
__global__ __launch_bounds__(256)
void qkv_gemm(const unsigned short* __restrict__ x_bf,
              const unsigned short* __restrict__ W_bf,
              const float* __restrict__ bq, const float* __restrict__ bk,
              const float* __restrict__ bv,
              unsigned short* __restrict__ Q_bf, unsigned short* __restrict__ K_bf,
              unsigned short* __restrict__ V_bf) {
    const int which = blockIdx.z;
    const unsigned short* A = x_bf + (size_t)which * (4u << 20);
    const unsigned short* W = W_bf + (size_t)which * (1u << 20);
    const float* bias = (which == 0) ? bq : (which == 1) ? bk : bv;
    unsigned short* dst = (which == 0) ? Q_bf : (which == 1) ? K_bf : V_bf;

    const int row0 = blockIdx.x * 128;
    const int col0 = blockIdx.y * 128;

    __shared__ unsigned short As[128 * 40];
    __shared__ unsigned short Bs[128 * 40];

    const int t = threadIdx.x;
    const int wid = t >> 6, lane = t & 63;
    const int wm = wid >> 1, wn = wid & 1;
    const int l = lane & 15, quad = lane >> 4;

    f32x4 acc[4][4];
#pragma unroll
    for (int i = 0; i < 4; ++i)
#pragma unroll
        for (int j = 0; j < 4; ++j) {
            float b_ = bias[col0 + wn * 64 + j * 16 + l];
            acc[i][j] = (f32x4){ b_, b_, b_, b_ };
        }

    for (int k0 = 0; k0 < DMODEL; k0 += 32) {
        uint4 ar[2], br[2];
#pragma unroll
        for (int i = 0; i < 2; ++i) {
            const int c = t + i * 256, r = c >> 2, q = (c & 3) * 8;
            ar[i] = *(const uint4*)(A + (size_t)(row0 + r) * DMODEL + k0 + q);
            br[i] = *(const uint4*)(W + (size_t)(col0 + r) * DMODEL + k0 + q);
        }
        __syncthreads();
#pragma unroll
        for (int i = 0; i < 2; ++i) {
            const int c = t + i * 256, r = c >> 2, q = (c & 3) * 8;
            *(uint4*)&As[r * 40 + q] = ar[i];
            *(uint4*)&Bs[r * 40 + q] = br[i];
        }
        __syncthreads();
        bf16x8 a[4], b[4];
#pragma unroll
        for (int i = 0; i < 4; ++i)
            a[i] = *(const bf16x8*)&As[(wm * 64 + i * 16 + l) * 40 + quad * 8];
#pragma unroll
        for (int j = 0; j < 4; ++j)
            b[j] = *(const bf16x8*)&Bs[(wn * 64 + j * 16 + l) * 40 + quad * 8];
#pragma unroll
        for (int i = 0; i < 4; ++i)
#pragma unroll
            for (int j = 0; j < 4; ++j)
                acc[i][j] = __builtin_amdgcn_mfma_f32_16x16x32_bf16(a[i], b[j], acc[i][j], 0, 0, 0);
    }

#pragma unroll
    for (int i = 0; i < 4; ++i)
#pragma unroll
        for (int r = 0; r < 4; ++r) {
            const int m = row0 + wm * 64 + i * 16 + quad * 4 + r;
            const int b_ = m >> 11, s = m & 2047;
#pragma unroll
            for (int j = 0; j < 4; ++j) {
                const int n = col0 + wn * 64 + j * 16 + l;
                const int h = n >> 6, d = n & 63;
                dst[(((size_t)(b_ * NHEAD + h)) * S_LEN + s) * 64 + d] = f2bf(acc[i][j][r]);
            }
        }
}

// ---------------- fused: logits (MFMA) + sparsemax (Newton waterfilling) + P@V
// grid (128 row-tiles, 32 bh), 512 threads = 8 waves.
// Wave w computes S[16 rows][cols w*256..+256) in regs (16 C-frags).
// Tau: row-max round; 2 full-sweep Newton steps (tau0=m-1 <= tau1 <= tau2 <= tau*);
// compact {z > tau2} (superset of support) to per-row LDS lists; 10 exact Newton
// iters on lists. P written once (only attn HBM traffic). PV reuses lists.
__global__ __launch_bounds__(512)
void fused_attn(const unsigned short* __restrict__ Q_bf,
                const unsigned short* __restrict__ K_bf,
                const unsigned short* __restrict__ V_bf,
                float* __restrict__ attn, unsigned short* __restrict__ AO_bf) {
    const int bh = blockIdx.y;
    const int m0 = blockIdx.x * 16;
    const unsigned short* Qh = Q_bf + (size_t)bh * HEAD_ELEMS;
    const unsigned short* Kh = K_bf + (size_t)bh * HEAD_ELEMS;
    const unsigned short* Vh = V_bf + (size_t)bh * HEAD_ELEMS;
    const int b_ = bh >> 4, h = bh & 15;

    __shared__ uint2 list[16][CAP];     // (col, z) candidates per row  (64 KB)
    __shared__ float stat[16][8][2];    // per-row per-wave partials
    __shared__ float drv[16];           // derived per-row value (tau stages)
    __shared__ int   cnt[16];

    const int t = threadIdx.x;
    const int w = t >> 6, lane = t & 63;
    const int l = lane & 15, quad = lane >> 4;

    if (t < 16) cnt[t] = 0;

    // ---- A frags: lane l -> Q row m0+l, k = quad*8..+7 and +32
    bf16x8 a0 = *(const bf16x8*)(Qh + (size_t)(m0 + l) * 64 + quad * 8);
    bf16x8 a1 = *(const bf16x8*)(Qh + (size_t)(m0 + l) * 64 + 32 + quad * 8);

    // ---- QK^T/8 for this wave's 256 cols: 16 N-tiles, K=64 (2 MFMA each)
    const int c0 = w * 256;
    f32x4 z[16];
#pragma unroll
    for (int nt = 0; nt < 16; ++nt) {
        const unsigned short* kr = Kh + (size_t)(c0 + nt * 16 + l) * 64;
        bf16x8 b0 = *(const bf16x8*)(kr + quad * 8);
        bf16x8 b1 = *(const bf16x8*)(kr + 32 + quad * 8);
        f32x4 acc = { 0.0f, 0.0f, 0.0f, 0.0f };
        acc = __builtin_amdgcn_mfma_f32_16x16x32_bf16(a0, b0, acc, 0, 0, 0);
        acc = __builtin_amdgcn_mfma_f32_16x16x32_bf16(a1, b1, acc, 0, 0, 0);
        z[nt] = acc * 0.125f;
    }
    // C/D layout: element (nt, r) of lane = S[row = quad*4+r][col = c0+nt*16+l]

    // ---- round 1: row max -> tau0 = m - 1
    {
        float mr[4];
#pragma unroll
        for (int r = 0; r < 4; ++r) {
            float v = z[0][r];
#pragma unroll
            for (int nt = 1; nt < 16; ++nt) v = fmaxf(v, z[nt][r]);
            v = fmaxf(v, __shfl_xor(v, 1, 64));
            v = fmaxf(v, __shfl_xor(v, 2, 64));
            v = fmaxf(v, __shfl_xor(v, 4, 64));
            v = fmaxf(v, __shfl_xor(v, 8, 64));
            mr[r] = v;
        }
        if (l == 0) {
#pragma unroll
            for (int r = 0; r < 4; ++r) stat[quad * 4 + r][w][0] = mr[r];
        }
        __syncthreads();
        if (w == 0 && lane < 16) {
            float m_ = stat[lane][0][0];
#pragma unroll
            for (int i = 1; i < 8; ++i) m_ = fmaxf(m_, stat[lane][i][0]);
            drv[lane] = m_ - 1.0f;
        }
        __syncthreads();
    }
    float tau_r[4];
#pragma unroll
    for (int r = 0; r < 4; ++r) tau_r[r] = drv[quad * 4 + r];

    // ---- rounds 2,3: full-sweep Newton (waterfilling from below)
#pragma unroll 1
    for (int it = 0; it < 2; ++it) {
        float s_[4] = {}, k_[4] = {};
#pragma unroll
        for (int nt = 0; nt < 16; ++nt)
#pragma unroll
            for (int r = 0; r < 4; ++r) {
                const float zz = z[nt][r];
                if (zz > tau_r[r]) { s_[r] += zz; k_[r] += 1.0f; }
            }
#pragma unroll
        for (int r = 0; r < 4; ++r) {
            s_[r] += __shfl_xor(s_[r], 1, 64); k_[r] += __shfl_xor(k_[r], 1, 64);
            s_[r] += __shfl_xor(s_[r], 2, 64); k_[r] += __shfl_xor(k_[r], 2, 64);
            s_[r] += __shfl_xor(s_[r], 4, 64); k_[r] += __shfl_xor(k_[r], 4, 64);
            s_[r] += __shfl_xor(s_[r], 8, 64); k_[r] += __shfl_xor(k_[r], 8, 64);
        }
        __syncthreads();   // protect stat[] reuse across rounds
        if (l == 0) {
#pragma unroll
            for (int r = 0; r < 4; ++r) {
                stat[quad * 4 + r][w][0] = s_[r];
                stat[quad * 4 + r][w][1] = k_[r];
            }
        }
        __syncthreads();
        if (w == 0 && lane < 16) {
            float s = 0.0f, k = 0.0f;
#pragma unroll
            for (int i = 0; i < 8; ++i) { s += stat[lane][i][0]; k += stat[lane][i][1]; }
            drv[lane] = (s - 1.0f) / k;
        }
        __syncthreads();
#pragma unroll
        for (int r = 0; r < 4; ++r) tau_r[r] = drv[quad * 4 + r];
    }

    // ---- compact candidates {z > tau2} into per-row lists
#pragma unroll
    for (int nt = 0; nt < 16; ++nt)
#pragma unroll
        for (int r = 0; r < 4; ++r) {
            const float zz = z[nt][r];
            if (zz > tau_r[r]) {
                const int row = quad * 4 + r;
                const int pos = atomicAdd(&cnt[row], 1);
                if (pos < CAP) {
                    uint2 e = { (unsigned)(c0 + nt * 16 + l),
                                __builtin_bit_cast(unsigned, zz) };
                    list[row][pos] = e;
                }
            }
        }
    __syncthreads();

    // ---- exact Newton on candidate lists: wave w owns rows 2w, 2w+1
#pragma unroll 1
    for (int rr = 0; rr < 2; ++rr) {
        const int row = w * 2 + rr;
        const int n = min(cnt[row], CAP);
        float zl[8];
#pragma unroll
        for (int i = 0; i < 8; ++i) {
            const int idx = lane + i * 64;
            zl[i] = (idx < n) ? __builtin_bit_cast(float, list[row][idx].y) : -1e30f;
        }
        float tau = drv[row];
#pragma unroll 1
        for (int it = 0; it < 10; ++it) {
            float s = 0.0f, k = 0.0f;
#pragma unroll
            for (int i = 0; i < 8; ++i)
                if (zl[i] > tau) { s += zl[i]; k += 1.0f; }
            s = wave_sum64(s); k = wave_sum64(k);
            tau = (s - 1.0f) / k;
        }
        if (lane == 0) drv[row] = tau;
    }
    __syncthreads();
#pragma unroll
    for (int r = 0; r < 4; ++r) tau_r[r] = drv[quad * 4 + r];

    // ---- P = relu(z - tau): the only attn HBM write (required output)
    float* ap = attn + (size_t)bh * S_LEN * S_LEN;
#pragma unroll
    for (int nt = 0; nt < 16; ++nt)
#pragma unroll
        for (int r = 0; r < 4; ++r) {
            const float p = fmaxf(z[nt][r] - tau_r[r], 0.0f);
            ap[(size_t)(m0 + quad * 4 + r) * S_LEN + c0 + nt * 16 + l] = p;
        }

    // ---- PV via lists (support subset of candidates); V rows L2-hot
#pragma unroll 1
    for (int rr = 0; rr < 2; ++rr) {
        const int row = w * 2 + rr;
        const float tau = drv[row];
        const int n = min(cnt[row], CAP);
        float a = 0.0f;
        int i = 0;
#pragma unroll 1
        for (; i + 2 <= n; i += 2) {
            uint2 e0 = list[row][i], e1 = list[row][i + 1];
            const float p0 = __builtin_bit_cast(float, e0.y) - tau;
            const float p1 = __builtin_bit_cast(float, e1.y) - tau;
            const float v0 = bf2f(Vh[(size_t)e0.x * 64 + lane]);
            const float v1 = bf2f(Vh[(size_t)e1.x * 64 + lane]);
            if (p0 > 0.0f) a += p0 * v0;
            if (p1 > 0.0f) a += p1 * v1;
        }
        if (i < n) {
            uint2 e0 = list[row][i];
            const float p0 = __builtin_bit_cast(float, e0.y) - tau;
            if (p0 > 0.0f) a += p0 * bf2f(Vh[(size_t)e0.x * 64 + lane]);
        }
        const int s = m0 + row;
        AO_bf[((size_t)(b_ * S_LEN + s)) * DMODEL + h * 64 + lane] = f2bf(a);
    }
}

// ------------------------------------------- out = AO @ Wfc^T + bfc (bf16 MFMA)
__global__ __launch_bounds__(256)
void fc_gemm(const unsigned short* __restrict__ AO_bf,
             const unsigned short* __restrict__ Wfc_bf,
             const float* __restrict__ bfc, float* __restrict__ out) {
    const int row0 = blockIdx.x * 128;
    const int col0 = blockIdx.y * 128;

    __shared__ unsigned short As[128 * 40];
    __shared__ unsigned short Bs[128 * 40];

    const int t = threadIdx.x;
    const int wid = t >> 6, lane = t & 63;
    const int wm = wid >> 1, wn = wid & 1;
    const int l = lane & 15, quad = lane >> 4;

    f32x4 acc[4][4];
#pragma unroll
    for (int i = 0; i < 4; ++i)
#pragma unroll
        for (int j = 0; j < 4; ++j) {
            float b_ = bfc[col0 + wn * 64 + j * 16 + l];
            acc[i][j] = (f32x4){ b_, b_, b_, b_ };
        }

    for (int k0 = 0; k0 < DMODEL; k0 += 32) {
        uint4 ar[2], br[2];
#pragma unroll
        for (int i = 0; i < 2; ++i) {
            const int c = t + i * 256, r = c >> 2, q = (c & 3) * 8;
            ar[i] = *(const uint4*)(AO_bf + (size_t)(row0 + r) * DMODEL + k0 + q);
            br[i] = *(const uint4*)(Wfc_bf + (size_t)(col0 + r) * DMODEL + k0 + q);
        }
        __syncthreads();
#pragma unroll
        for (int i = 0; i < 2; ++i) {
            const int c = t + i * 256, r = c >> 2, q = (c & 3) * 8;
            *(uint4*)&As[r * 40 + q] = ar[i];
            *(uint4*)&Bs[r * 40 + q] = br[i];
        }
        __syncthreads();
        bf16x8 a[4], b[4];
#pragma unroll
        for (int i = 0; i < 4; ++i)
            a[i] = *(const bf16x8*)&As[(wm * 64 + i * 16 + l) * 40 + quad * 8];
#pragma unroll
        for (int j = 0; j < 4; ++j)
            b[j] = *(const bf16x8*)&Bs[(wn * 64 + j * 16 + l) * 40 + quad * 8];
#pragma unroll
        for (int i = 0; i < 4; ++i)
#pragma unroll
            for (int j = 0; j < 4; ++j)
                acc[i][j] = __builtin_amdgcn_mfma_f32_16x16x32_bf16(a[i], b[j], acc[i][j], 0, 0, 0);
    }

#pragma unroll
    for (int i = 0; i < 4; ++i)
#pragma unroll
        for (int r = 0; r < 4; ++r) {
            const int m = row0 + wm * 64 + i * 16 + quad * 4 + r;
#pragma unroll
            for (int j = 0; j < 4; ++j) {
                const int n = col0 + wn * 64 + j * 16 + l;
                out[(size_t)m * DMODEL + n] = acc[i][j][r];
            }
        }
}

// ----------------------------------------------------------------------- launch
extern "C" void kernel_launch(void* const* d_in, const int* in_sizes, int n_in,
                              void* d_out, int out_size, void* d_ws, size_t ws_size,
                              hipStream_t stream) {
    const float* q   = (const float*)d_in[0];
    const float* k   = (const float*)d_in[1];
    const float* v   = (const float*)d_in[2];
    const float* Wq  = (const float*)d_in[3];
    const float* bq  = (const float*)d_in[4];
    const float* Wk  = (const float*)d_in[5];
    const float* bk  = (const float*)d_in[6];
    const float* Wv  = (const float*)d_in[7];
    const float* bv  = (const float*)d_in[8];
    const float* Wfc = (const float*)d_in[9];
    const float* bfc = (const float*)d_in[10];

    float* out  = (float*)d_out;                       // [B,S,D] fp32
    float* attn = out + (size_t)M_ROWS * DMODEL;       // [B,H,S,S] fp32

    // workspace:
    //  [ 0,24M): x_bf (xq,xk,xv)   -- later: [0,8M)=AO_bf alias (qkv reads done)
    //  [24,32M): W_bf (Wq,Wk,Wv,Wfc)
    //  [32,40M): Q_bf   [40,48M): K_bf   [48,56M): V_bf
    char* ws = (char*)d_ws;
    unsigned short* x_bf = (unsigned short*)ws;
    unsigned short* W_bf = (unsigned short*)(ws + (24u << 20));
    unsigned short* Q_bf = (unsigned short*)(ws + (32u << 20));
    unsigned short* K_bf = (unsigned short*)(ws + (40u << 20));
    unsigned short* V_bf = (unsigned short*)(ws + (48u << 20));
    unsigned short* AO_bf = x_bf;                      // aliases xq_bf (safe: qkv done)

    cast_kernel<<<16384, 256, 0, stream>>>(q, k, v, Wq, Wk, Wv, Wfc, x_bf);
    qkv_gemm<<<dim3(32, 8, 3), 256, 0, stream>>>(x_bf, W_bf, bq, bk, bv, Q_bf, K_bf, V_bf);
    fused_attn<<<dim3(128, 32), 512, 0, stream>>>(Q_bf, K_bf, V_bf, attn, AO_bf);
    fc_gemm<<<dim3(32, 8), 256, 0, stream>>>(AO_bf, W_bf + (3u << 20), bfc, out);
}

// Round 5
// 991.708 us; speedup vs baseline: 1.6027x; 1.6027x over previous
//
#include <hip/hip_runtime.h>
#include <hip/hip_bf16.h>
#include <cstdint>

// MultiHeadAttention w/ sparsemax: B=2, S=2048, D=1024, H=16, DK=64
#define S_LEN  2048
#define DMODEL 1024
#define NHEAD  16
#define M_ROWS 4096                       // B*S
#define HEAD_ELEMS (2048u * 64u)          // per (b,h) Q/K/V elems

typedef __attribute__((ext_vector_type(8))) short bf16x8;   // MFMA A/B frag (8 bf16)
typedef __attribute__((ext_vector_type(4))) float f32x4;    // MFMA C/D frag

__device__ __forceinline__ unsigned short f2bf(float f) {
    __hip_bfloat16 h = __float2bfloat16(f);
    return __builtin_bit_cast(unsigned short, h);
}
__device__ __forceinline__ float bf2f(unsigned short u) {
    return __builtin_bit_cast(float, (unsigned)u << 16);
}

// ---------------------------------------------------------------- wave reduce
__device__ __forceinline__ float wave_sum64(float v) {
    v += __shfl_xor(v, 32, 64); v += __shfl_xor(v, 16, 64);
    v += __shfl_xor(v, 8, 64);  v += __shfl_xor(v, 4, 64);
    v += __shfl_xor(v, 2, 64);  v += __shfl_xor(v, 1, 64);
    return v;
}
__device__ __forceinline__ float wave_max64(float v) {
    v = fmaxf(v, __shfl_xor(v, 32, 64)); v = fmaxf(v, __shfl_xor(v, 16, 64));
    v = fmaxf(v, __shfl_xor(v, 8, 64));  v = fmaxf(v, __shfl_xor(v, 4, 64));
    v = fmaxf(v, __shfl_xor(v, 2, 64));  v = fmaxf(v, __shfl_xor(v, 1, 64));
    return v;
}
__device__ __forceinline__ int lanes_below(unsigned long long m) {
    return __builtin_amdgcn_mbcnt_hi((unsigned)(m >> 32),
           __builtin_amdgcn_mbcnt_lo((unsigned)m, 0));
}

// --------------------------------------------------------------- cast fp32->bf16
// 16M elems: [0,4M)=xq [4M,8M)=xk [8M,12M)=xv [12M,13M)=Wq [13M,14M)=Wk
// [14M,15M)=Wv [15M,16M)=Wfc. Output contiguous bf16 at ws+0.
__global__ __launch_bounds__(256)
void cast_kernel(const float* __restrict__ xq, const float* __restrict__ xk,
                 const float* __restrict__ xv, const float* __restrict__ Wq,
                 const float* __restrict__ Wk, const float* __restrict__ Wv,
                 const float* __restrict__ Wfc, unsigned short* __restrict__ out) {
    const size_t e = ((size_t)blockIdx.x * 256 + threadIdx.x) * 4;
    const size_t M1 = 1u << 20, M4 = 4u << 20;
    const float* src; size_t off;
    if      (e < M4)        { src = xq;  off = e; }
    else if (e < 2 * M4)    { src = xk;  off = e - M4; }
    else if (e < 3 * M4)    { src = xv;  off = e - 2 * M4; }
    else if (e < 13 * M1)   { src = Wq;  off = e - 3 * M4; }
    else if (e < 14 * M1)   { src = Wk;  off = e - 13 * M1; }
    else if (e < 15 * M1)   { src = Wv;  off = e - 14 * M1; }
    else                    { src = Wfc; off = e - 15 * M1; }
    float4 v = *(const float4*)(src + off);
    unsigned int lo = ((unsigned)f2bf(v.y) << 16) | f2bf(v.x);
    unsigned int hi = ((unsigned)f2bf(v.w) << 16) | f2bf(v.z);
    uint2 st = { lo, hi };
    *(uint2*)(out + e) = st;
}

// ------------------------------------------------- qkv: C = A@W^T + b (bf16 MFMA)
// A[4096,1024] bf16, W[1024,1024] bf16 (NT). Output head-major bf16 [B,H,S,64].
__global__ __launch_bounds__(256)
void qkv_gemm(const unsigned short* __restrict__ x_bf,
              const unsigned short* __restrict__ W_bf,
              const float* __restrict__ bq, const float* __restrict__ bk,
              const float* __restrict__ bv,
              unsigned short* __restrict__ Q_bf, unsigned short* __restrict__ K_bf,
              unsigned short* __restrict__ V_bf) {
    const int which = blockIdx.z;
    const unsigned short* A = x_bf + (size_t)which * (4u << 20);
    const unsigned short* W = W_bf + (size_t)which * (1u << 20);
    const float* bias = (which == 0) ? bq : (which == 1) ? bk : bv;
    unsigned short* dst = (which == 0) ? Q_bf : (which == 1) ? K_bf : V_bf;

    const int row0 = blockIdx.x * 128;
    const int col0 = blockIdx.y * 128;

    __shared__ unsigned short As[128 * 40];   // stride 40 bf16 = 80 B (2-way free)
    __shared__ unsigned short Bs[128 * 40];

    const int t = threadIdx.x;
    const int wid = t >> 6, lane = t & 63;
    const int wm = wid >> 1, wn = wid & 1;
    const int l = lane & 15, quad = lane >> 4;

    f32x4 acc[4][4];
#pragma unroll
    for (int i = 0; i < 4; ++i)
#pragma unroll
        for (int j = 0; j < 4; ++j) {
            float b_ = bias[col0 + wn * 64 + j * 16 + l];
            acc[i][j] = (f32x4){ b_, b_, b_, b_ };
        }

    for (int k0 = 0; k0 < DMODEL; k0 += 32) {
        uint4 ar[2], br[2];
#pragma unroll
        for (int i = 0; i < 2; ++i) {
            const int c = t + i * 256, r = c >> 2, q = (c & 3) * 8;
            ar[i] = *(const uint4*)(A + (size_t)(row0 + r) * DMODEL + k0 + q);
            br[i] = *(const uint4*)(W + (size_t)(col0 + r) * DMODEL + k0 + q);
        }
        __syncthreads();
#pragma unroll
        for (int i = 0; i < 2; ++i) {
            const int c = t + i * 256, r = c >> 2, q = (c & 3) * 8;
            *(uint4*)&As[r * 40 + q] = ar[i];
            *(uint4*)&Bs[r * 40 + q] = br[i];
        }
        __syncthreads();
        bf16x8 a[4], b[4];
#pragma unroll
        for (int i = 0; i < 4; ++i)
            a[i] = *(const bf16x8*)&As[(wm * 64 + i * 16 + l) * 40 + quad * 8];
#pragma unroll
        for (int j = 0; j < 4; ++j)
            b[j] = *(const bf16x8*)&Bs[(wn * 64 + j * 16 + l) * 40 + quad * 8];
#pragma unroll
        for (int i = 0; i < 4; ++i)
#pragma unroll
            for (int j = 0; j < 4; ++j)
                acc[i][j] = __builtin_amdgcn_mfma_f32_16x16x32_bf16(a[i], b[j], acc[i][j], 0, 0, 0);
    }

    // scatter bf16 to [B,H,S,64]
#pragma unroll
    for (int i = 0; i < 4; ++i)
#pragma unroll
        for (int r = 0; r < 4; ++r) {
            const int m = row0 + wm * 64 + i * 16 + quad * 4 + r;
            const int b_ = m >> 11, s = m & 2047;
#pragma unroll
            for (int j = 0; j < 4; ++j) {
                const int n = col0 + wn * 64 + j * 16 + l;
                const int h = n >> 6, d = n & 63;
                dst[(((size_t)(b_ * NHEAD + h)) * S_LEN + s) * 64 + d] = f2bf(acc[i][j][r]);
            }
        }
}

// --------------------------------------------- logits = Q@K^T / 8 (bf16 MFMA, K=64)
__global__ __launch_bounds__(256)
void logits_gemm(const unsigned short* __restrict__ Q_bf,
                 const unsigned short* __restrict__ K_bf,
                 float* __restrict__ attn) {
    const int bh = blockIdx.z;
    const unsigned short* Qh = Q_bf + (size_t)bh * HEAD_ELEMS;
    const unsigned short* Kh = K_bf + (size_t)bh * HEAD_ELEMS;
    const int row0 = blockIdx.x * 128;
    const int col0 = blockIdx.y * 128;

    __shared__ unsigned short As[128 * 72];   // stride 72 bf16 = 144 B
    __shared__ unsigned short Bs[128 * 72];

    const int t = threadIdx.x;
    const int wid = t >> 6, lane = t & 63;
    const int wm = wid >> 1, wn = wid & 1;
    const int l = lane & 15, quad = lane >> 4;

#pragma unroll
    for (int i = 0; i < 4; ++i) {
        const int c = t + i * 256, r = c >> 3, q = (c & 7) * 8;
        *(uint4*)&As[r * 72 + q] = *(const uint4*)(Qh + (size_t)(row0 + r) * 64 + q);
        *(uint4*)&Bs[r * 72 + q] = *(const uint4*)(Kh + (size_t)(col0 + r) * 64 + q);
    }
    __syncthreads();

    f32x4 acc[4][4] = {};
#pragma unroll
    for (int kk = 0; kk < 64; kk += 32) {
        bf16x8 a[4], b[4];
#pragma unroll
        for (int i = 0; i < 4; ++i)
            a[i] = *(const bf16x8*)&As[(wm * 64 + i * 16 + l) * 72 + kk + quad * 8];
#pragma unroll
        for (int j = 0; j < 4; ++j)
            b[j] = *(const bf16x8*)&Bs[(wn * 64 + j * 16 + l) * 72 + kk + quad * 8];
#pragma unroll
        for (int i = 0; i < 4; ++i)
#pragma unroll
            for (int j = 0; j < 4; ++j)
                acc[i][j] = __builtin_amdgcn_mfma_f32_16x16x32_bf16(a[i], b[j], acc[i][j], 0, 0, 0);
    }

    float* ap = attn + (size_t)bh * S_LEN * S_LEN;
#pragma unroll
    for (int i = 0; i < 4; ++i)
#pragma unroll
        for (int r = 0; r < 4; ++r) {
            const int m = row0 + wm * 64 + i * 16 + quad * 4 + r;
#pragma unroll
            for (int j = 0; j < 4; ++j) {
                const int n = col0 + wn * 64 + j * 16 + l;
                ap[(size_t)m * S_LEN + n] = acc[i][j][r] * 0.125f;
            }
        }
}

// ---------------------------------------- fused sparsemax + P@V (per-row wave)
// In-place S -> P on attn rows; PV via sparse compaction (support << 2048).
// Tau by Newton waterfilling from below: tau0 = max-1; tau <- (sum_{z>tau}-1)/k.
// Monotone non-overshooting; once support stabilizes the iterate IS the exact
// tau (fixed point), so no refine pass. 8 iters (converges in ~3-4).
__global__ __launch_bounds__(256)
void smpv_kernel(float* __restrict__ attn, const unsigned short* __restrict__ V_bf,
                 unsigned short* __restrict__ AO_bf) {
    const int wave = threadIdx.x >> 6;
    const int lane = threadIdx.x & 63;
    const size_t row = (size_t)blockIdx.x * 4 + wave;   // [0, 65536)
    const int bh = (int)(row >> 11), s = (int)(row & 2047);
    const int b_ = bh >> 4, h = bh & 15;
    float4* rp = (float4*)(attn + row * S_LEN);
    const unsigned short* Vh = V_bf + (size_t)bh * HEAD_ELEMS;  // [2048,64]

    __shared__ uint2 list[4][512];   // per-wave (col, p) compaction buffer

    // ---- load row: z[4r+j] lives at col r*256 + lane*4 + j
    float z[32];
#pragma unroll
    for (int r = 0; r < 8; ++r) {
        float4 v = rp[r * 64 + lane];
        z[4 * r + 0] = v.x; z[4 * r + 1] = v.y;
        z[4 * r + 2] = v.z; z[4 * r + 3] = v.w;
    }
    float m = z[0];
#pragma unroll
    for (int j = 1; j < 32; ++j) m = fmaxf(m, z[j]);
    m = wave_max64(m);

    // ---- Newton waterfilling (exact at fixed point)
    float tau = m - 1.0f;
#pragma unroll 1
    for (int it = 0; it < 8; ++it) {
        float ss = 0.0f, kk = 0.0f;
#pragma unroll
        for (int j = 0; j < 32; ++j)
            if (z[j] > tau) { ss += z[j]; kk += 1.0f; }
        ss = wave_sum64(ss); kk = wave_sum64(kk);
        tau = (ss - 1.0f) / kk;    // uniform across lanes -> no divergence
    }

    // ---- P = relu(z - tau): write back in place (required output)
#pragma unroll
    for (int j = 0; j < 32; ++j) z[j] = fmaxf(z[j] - tau, 0.0f);
#pragma unroll
    for (int r = 0; r < 8; ++r) {
        float4 v = { z[4 * r + 0], z[4 * r + 1], z[4 * r + 2], z[4 * r + 3] };
        rp[r * 64 + lane] = v;
    }

    // ---- PV: out[d=lane] = sum_k p_k * V[k][d], via per-round compaction
    float acc = 0.0f;
#pragma unroll 1
    for (int rr = 0; rr < 4; ++rr) {               // rounds of 8 elems/lane
        int base = 0;
#pragma unroll
        for (int e = 0; e < 8; ++e) {
            const int r = rr * 2 + (e >> 2), jj = e & 3;
            const float pv = z[4 * r + jj];
            const unsigned long long mk = __ballot(pv > 0.0f);
            if (pv > 0.0f) {
                const int pos = base + lanes_below(mk);
                uint2 kp = { (unsigned)(r * 256 + lane * 4 + jj),
                             __builtin_bit_cast(unsigned, pv) };
                list[wave][pos] = kp;
            }
            base += __popcll(mk);
        }
        __threadfence_block();                     // LDS writes -> reads (in-wave)
        const int total = base;
        int i = 0;
        for (; i + 2 <= total; i += 2) {
            uint2 kp0 = list[wave][i], kp1 = list[wave][i + 1];
            float v0 = bf2f(Vh[(size_t)kp0.x * 64 + lane]);
            float v1 = bf2f(Vh[(size_t)kp1.x * 64 + lane]);
            acc += __builtin_bit_cast(float, kp0.y) * v0;
            acc += __builtin_bit_cast(float, kp1.y) * v1;
        }
        if (i < total) {
            uint2 kp0 = list[wave][i];
            acc += __builtin_bit_cast(float, kp0.y) * bf2f(Vh[(size_t)kp0.x * 64 + lane]);
        }
        __threadfence_block();                     // reads done before next round's writes
    }

    AO_bf[((size_t)(b_ * S_LEN + s)) * DMODEL + h * 64 + lane] = f2bf(acc);
}

// ------------------------------------------- out = AO @ Wfc^T + bfc (bf16 MFMA)
__global__ __launch_bounds__(256)
void fc_gemm(const unsigned short* __restrict__ AO_bf,
             const unsigned short* __restrict__ Wfc_bf,
             const float* __restrict__ bfc, float* __restrict__ out) {
    const int row0 = blockIdx.x * 128;
    const int col0 = blockIdx.y * 128;

    __shared__ unsigned short As[128 * 40];
    __shared__ unsigned short Bs[128 * 40];

    const int t = threadIdx.x;
    const int wid = t >> 6, lane = t & 63;
    const int wm = wid >> 1, wn = wid & 1;
    const int l = lane & 15, quad = lane >> 4;

    f32x4 acc[4][4];
#pragma unroll
    for (int i = 0; i < 4; ++i)
#pragma unroll
        for (int j = 0; j < 4; ++j) {
            float b_ = bfc[col0 + wn * 64 + j * 16 + l];
            acc[i][j] = (f32x4){ b_, b_, b_, b_ };
        }

    for (int k0 = 0; k0 < DMODEL; k0 += 32) {
        uint4 ar[2], br[2];
#pragma unroll
        for (int i = 0; i < 2; ++i) {
            const int c = t + i * 256, r = c >> 2, q = (c & 3) * 8;
            ar[i] = *(const uint4*)(AO_bf + (size_t)(row0 + r) * DMODEL + k0 + q);
            br[i] = *(const uint4*)(Wfc_bf + (size_t)(col0 + r) * DMODEL + k0 + q);
        }
        __syncthreads();
#pragma unroll
        for (int i = 0; i < 2; ++i) {
            const int c = t + i * 256, r = c >> 2, q = (c & 3) * 8;
            *(uint4*)&As[r * 40 + q] = ar[i];
            *(uint4*)&Bs[r * 40 + q] = br[i];
        }
        __syncthreads();
        bf16x8 a[4], b[4];
#pragma unroll
        for (int i = 0; i < 4; ++i)
            a[i] = *(const bf16x8*)&As[(wm * 64 + i * 16 + l) * 40 + quad * 8];
#pragma unroll
        for (int j = 0; j < 4; ++j)
            b[j] = *(const bf16x8*)&Bs[(wn * 64 + j * 16 + l) * 40 + quad * 8];
#pragma unroll
        for (int i = 0; i < 4; ++i)
#pragma unroll
            for (int j = 0; j < 4; ++j)
                acc[i][j] = __builtin_amdgcn_mfma_f32_16x16x32_bf16(a[i], b[j], acc[i][j], 0, 0, 0);
    }

#pragma unroll
    for (int i = 0; i < 4; ++i)
#pragma unroll
        for (int r = 0; r < 4; ++r) {
            const int m = row0 + wm * 64 + i * 16 + quad * 4 + r;
#pragma unroll
            for (int j = 0; j < 4; ++j) {
                const int n = col0 + wn * 64 + j * 16 + l;
                out[(size_t)m * DMODEL + n] = acc[i][j][r];
            }
        }
}

// ----------------------------------------------------------------------- launch
extern "C" void kernel_launch(void* const* d_in, const int* in_sizes, int n_in,
                              void* d_out, int out_size, void* d_ws, size_t ws_size,
                              hipStream_t stream) {
    const float* q   = (const float*)d_in[0];
    const float* k   = (const float*)d_in[1];
    const float* v   = (const float*)d_in[2];
    const float* Wq  = (const float*)d_in[3];
    const float* bq  = (const float*)d_in[4];
    const float* Wk  = (const float*)d_in[5];
    const float* bk  = (const float*)d_in[6];
    const float* Wv  = (const float*)d_in[7];
    const float* bv  = (const float*)d_in[8];
    const float* Wfc = (const float*)d_in[9];
    const float* bfc = (const float*)d_in[10];

    float* out  = (float*)d_out;                       // [B,S,D] fp32
    float* attn = out + (size_t)M_ROWS * DMODEL;       // [B,H,S,S] fp32

    // workspace:
    //  [ 0,24M): x_bf (xq,xk,xv)   -- later: [0,8M)=AO_bf alias (qkv reads done)
    //  [24,32M): W_bf (Wq,Wk,Wv,Wfc)
    //  [32,40M): Q_bf   [40,48M): K_bf   [48,56M): V_bf
    char* ws = (char*)d_ws;
    unsigned short* x_bf = (unsigned short*)ws;
    unsigned short* W_bf = (unsigned short*)(ws + (24u << 20));
    unsigned short* Q_bf = (unsigned short*)(ws + (32u << 20));
    unsigned short* K_bf = (unsigned short*)(ws + (40u << 20));
    unsigned short* V_bf = (unsigned short*)(ws + (48u << 20));
    unsigned short* AO_bf = x_bf;                      // aliases xq_bf (safe: qkv done)

    cast_kernel<<<16384, 256, 0, stream>>>(q, k, v, Wq, Wk, Wv, Wfc, x_bf);
    qkv_gemm<<<dim3(32, 8, 3), 256, 0, stream>>>(x_bf, W_bf, bq, bk, bv, Q_bf, K_bf, V_bf);
    logits_gemm<<<dim3(16, 16, 32), 256, 0, stream>>>(Q_bf, K_bf, attn);
    smpv_kernel<<<16384, 256, 0, stream>>>(attn, V_bf, AO_bf);
    fc_gemm<<<dim3(32, 8), 256, 0, stream>>>(AO_bf, W_bf + (3u << 20), bfc, out);
}

// Round 6
// 907.788 us; speedup vs baseline: 1.7509x; 1.0924x over previous
//
#include <hip/hip_runtime.h>
#include <hip/hip_bf16.h>
#include <cstdint>

// MultiHeadAttention w/ sparsemax: B=2, S=2048, D=1024, H=16, DK=64
#define S_LEN  2048
#define DMODEL 1024
#define NHEAD  16
#define M_ROWS 4096                       // B*S

typedef __attribute__((ext_vector_type(8))) short bf16x8;   // MFMA A/B frag (8 bf16)
typedef __attribute__((ext_vector_type(4))) float f32x4;    // MFMA C/D frag

__device__ __forceinline__ unsigned short f2bf(float f) {
    __hip_bfloat16 h = __float2bfloat16(f);
    return __builtin_bit_cast(unsigned short, h);
}
__device__ __forceinline__ float bf2f(unsigned short u) {
    return __builtin_bit_cast(float, (unsigned)u << 16);
}
__device__ __forceinline__ uint4 pack8(float4 a, float4 b) {
    uint4 u;
    u.x = ((unsigned)f2bf(a.y) << 16) | f2bf(a.x);
    u.y = ((unsigned)f2bf(a.w) << 16) | f2bf(a.z);
    u.z = ((unsigned)f2bf(b.y) << 16) | f2bf(b.x);
    u.w = ((unsigned)f2bf(b.w) << 16) | f2bf(b.z);
    return u;
}

// ---------------------------------------------------------------- wave reduce
__device__ __forceinline__ float wave_sum64(float v) {
    v += __shfl_xor(v, 32, 64); v += __shfl_xor(v, 16, 64);
    v += __shfl_xor(v, 8, 64);  v += __shfl_xor(v, 4, 64);
    v += __shfl_xor(v, 2, 64);  v += __shfl_xor(v, 1, 64);
    return v;
}
__device__ __forceinline__ float wave_max64(float v) {
    v = fmaxf(v, __shfl_xor(v, 32, 64)); v = fmaxf(v, __shfl_xor(v, 16, 64));
    v = fmaxf(v, __shfl_xor(v, 8, 64));  v = fmaxf(v, __shfl_xor(v, 4, 64));
    v = fmaxf(v, __shfl_xor(v, 2, 64));  v = fmaxf(v, __shfl_xor(v, 1, 64));
    return v;
}
__device__ __forceinline__ int lanes_below(unsigned long long m) {
    return __builtin_amdgcn_mbcnt_hi((unsigned)(m >> 32),
           __builtin_amdgcn_mbcnt_lo((unsigned)m, 0));
}

// ------------------------------------- qkv: C = A@W^T + b (fp32 in, bf16 MFMA)
// A[4096,1024] fp32, W[1024,1024] fp32 (NT); inline fp32->bf16 in staging.
// Output row-major bf16 [B,S,DMODEL] via LDS-transpose epilogue (16B stores).
__global__ __launch_bounds__(256)
void qkv_gemm(const float* __restrict__ xq, const float* __restrict__ xk,
              const float* __restrict__ xv,
              const float* __restrict__ Wq, const float* __restrict__ Wk,
              const float* __restrict__ Wv,
              const float* __restrict__ bq, const float* __restrict__ bk,
              const float* __restrict__ bv,
              unsigned short* __restrict__ Q_bf, unsigned short* __restrict__ K_bf,
              unsigned short* __restrict__ V_bf) {
    const int which = blockIdx.z;
    const float* A    = (which == 0) ? xq : (which == 1) ? xk : xv;
    const float* W    = (which == 0) ? Wq : (which == 1) ? Wk : Wv;
    const float* bias = (which == 0) ? bq : (which == 1) ? bk : bv;
    unsigned short* dst = (which == 0) ? Q_bf : (which == 1) ? K_bf : V_bf;

    const int row0 = blockIdx.x * 128;
    const int col0 = blockIdx.y * 128;

    __shared__ unsigned short SMEM[10240];    // As(5120) + Bs(5120); epilogue aliases
    unsigned short* As = SMEM;                // stride 40 bf16 (2-way free)
    unsigned short* Bs = SMEM + 5120;

    const int t = threadIdx.x;
    const int wid = t >> 6, lane = t & 63;
    const int wm = wid >> 1, wn = wid & 1;
    const int l = lane & 15, quad = lane >> 4;

    f32x4 acc[4][4];
#pragma unroll
    for (int i = 0; i < 4; ++i)
#pragma unroll
        for (int j = 0; j < 4; ++j) {
            float b_ = bias[col0 + wn * 64 + j * 16 + l];
            acc[i][j] = (f32x4){ b_, b_, b_, b_ };
        }

    for (int k0 = 0; k0 < DMODEL; k0 += 32) {
        uint4 ar[2], br[2];
#pragma unroll
        for (int i = 0; i < 2; ++i) {
            const int c = t + i * 256, r = c >> 2, q = (c & 3) * 8;
            const float* ap = A + (size_t)(row0 + r) * DMODEL + k0 + q;
            const float* wp = W + (size_t)(col0 + r) * DMODEL + k0 + q;
            float4 a0 = *(const float4*)ap, a1 = *(const float4*)(ap + 4);
            float4 w0 = *(const float4*)wp, w1 = *(const float4*)(wp + 4);
            ar[i] = pack8(a0, a1);
            br[i] = pack8(w0, w1);
        }
        __syncthreads();
#pragma unroll
        for (int i = 0; i < 2; ++i) {
            const int c = t + i * 256, r = c >> 2, q = (c & 3) * 8;
            *(uint4*)&As[r * 40 + q] = ar[i];
            *(uint4*)&Bs[r * 40 + q] = br[i];
        }
        __syncthreads();
        bf16x8 a[4], b[4];
#pragma unroll
        for (int i = 0; i < 4; ++i)
            a[i] = *(const bf16x8*)&As[(wm * 64 + i * 16 + l) * 40 + quad * 8];
#pragma unroll
        for (int j = 0; j < 4; ++j)
            b[j] = *(const bf16x8*)&Bs[(wn * 64 + j * 16 + l) * 40 + quad * 8];
#pragma unroll
        for (int i = 0; i < 4; ++i)
#pragma unroll
            for (int j = 0; j < 4; ++j)
                acc[i][j] = __builtin_amdgcn_mfma_f32_16x16x32_bf16(a[i], b[j], acc[i][j], 0, 0, 0);
    }

    // ---- epilogue: acc -> LDS (bf16, stride 72 = 16B-aligned rows) -> uint4 stores
    __syncthreads();
    unsigned short* Cs = SMEM;                // 128*72 = 9216 <= 10240
#pragma unroll 1
    for (int jh = 0; jh < 2; ++jh) {
        if (wn == jh) {
#pragma unroll
            for (int i = 0; i < 4; ++i)
#pragma unroll
                for (int j = 0; j < 4; ++j)
#pragma unroll
                    for (int r = 0; r < 4; ++r)
                        Cs[(wm * 64 + i * 16 + quad * 4 + r) * 72 + j * 16 + l] =
                            f2bf(acc[i][j][r]);
        }
        __syncthreads();
#pragma unroll
        for (int it = 0; it < 4; ++it) {
            const int idx = t + it * 256;           // 0..1023
            const int row = idx >> 3, c8 = (idx & 7) * 8;
            *(uint4*)(dst + (size_t)(row0 + row) * DMODEL + col0 + jh * 64 + c8) =
                *(const uint4*)&Cs[row * 72 + c8];
        }
        __syncthreads();
    }
}

// --------------------------------------------- logits = Q@K^T / 8 (bf16 MFMA, K=64)
// Q/K row-major [B,S,D]; head slice = cols h*64..h*64+63, row stride DMODEL.
__global__ __launch_bounds__(256)
void logits_gemm(const unsigned short* __restrict__ Q_bf,
                 const unsigned short* __restrict__ K_bf,
                 float* __restrict__ attn) {
    const int bh = blockIdx.z;
    const int b_ = bh >> 4, h = bh & 15;
    const unsigned short* Qh = Q_bf + ((size_t)b_ * S_LEN) * DMODEL + h * 64;
    const unsigned short* Kh = K_bf + ((size_t)b_ * S_LEN) * DMODEL + h * 64;
    const int row0 = blockIdx.x * 128;
    const int col0 = blockIdx.y * 128;

    __shared__ unsigned short As[128 * 72];   // stride 72 bf16 = 144 B
    __shared__ unsigned short Bs[128 * 72];

    const int t = threadIdx.x;
    const int wid = t >> 6, lane = t & 63;
    const int wm = wid >> 1, wn = wid & 1;
    const int l = lane & 15, quad = lane >> 4;

#pragma unroll
    for (int i = 0; i < 4; ++i) {
        const int c = t + i * 256, r = c >> 3, q = (c & 7) * 8;
        *(uint4*)&As[r * 72 + q] = *(const uint4*)(Qh + (size_t)(row0 + r) * DMODEL + q);
        *(uint4*)&Bs[r * 72 + q] = *(const uint4*)(Kh + (size_t)(col0 + r) * DMODEL + q);
    }
    __syncthreads();

    f32x4 acc[4][4] = {};
#pragma unroll
    for (int kk = 0; kk < 64; kk += 32) {
        bf16x8 a[4], b[4];
#pragma unroll
        for (int i = 0; i < 4; ++i)
            a[i] = *(const bf16x8*)&As[(wm * 64 + i * 16 + l) * 72 + kk + quad * 8];
#pragma unroll
        for (int j = 0; j < 4; ++j)
            b[j] = *(const bf16x8*)&Bs[(wn * 64 + j * 16 + l) * 72 + kk + quad * 8];
#pragma unroll
        for (int i = 0; i < 4; ++i)
#pragma unroll
            for (int j = 0; j < 4; ++j)
                acc[i][j] = __builtin_amdgcn_mfma_f32_16x16x32_bf16(a[i], b[j], acc[i][j], 0, 0, 0);
    }

    float* ap = attn + (size_t)bh * S_LEN * S_LEN;
#pragma unroll
    for (int i = 0; i < 4; ++i)
#pragma unroll
        for (int r = 0; r < 4; ++r) {
            const int m = row0 + wm * 64 + i * 16 + quad * 4 + r;
#pragma unroll
            for (int j = 0; j < 4; ++j) {
                const int n = col0 + wn * 64 + j * 16 + l;
                ap[(size_t)m * S_LEN + n] = acc[i][j][r] * 0.125f;
            }
        }
}

// ---------------------------------------- fused sparsemax + P@V (per-row wave)
// Tau by Newton waterfilling from below (monotone; fixed point is exact tau).
__global__ __launch_bounds__(256)
void smpv_kernel(float* __restrict__ attn, const unsigned short* __restrict__ V_bf,
                 unsigned short* __restrict__ AO_bf) {
    const int wave = threadIdx.x >> 6;
    const int lane = threadIdx.x & 63;
    const size_t row = (size_t)blockIdx.x * 4 + wave;   // [0, 65536)
    const int bh = (int)(row >> 11), s = (int)(row & 2047);
    const int b_ = bh >> 4, h = bh & 15;
    float4* rp = (float4*)(attn + row * S_LEN);
    const unsigned short* Vh = V_bf + ((size_t)b_ * S_LEN) * DMODEL + h * 64;

    __shared__ uint2 list[4][512];   // per-wave (col, p) compaction buffer

    float z[32];
#pragma unroll
    for (int r = 0; r < 8; ++r) {
        float4 v = rp[r * 64 + lane];
        z[4 * r + 0] = v.x; z[4 * r + 1] = v.y;
        z[4 * r + 2] = v.z; z[4 * r + 3] = v.w;
    }
    float m = z[0];
#pragma unroll
    for (int j = 1; j < 32; ++j) m = fmaxf(m, z[j]);
    m = wave_max64(m);

    float tau = m - 1.0f;
#pragma unroll 1
    for (int it = 0; it < 8; ++it) {
        float ss = 0.0f, kk = 0.0f;
#pragma unroll
        for (int j = 0; j < 32; ++j)
            if (z[j] > tau) { ss += z[j]; kk += 1.0f; }
        ss = wave_sum64(ss); kk = wave_sum64(kk);
        tau = (ss - 1.0f) / kk;    // uniform across lanes -> no divergence
    }

#pragma unroll
    for (int j = 0; j < 32; ++j) z[j] = fmaxf(z[j] - tau, 0.0f);
#pragma unroll
    for (int r = 0; r < 8; ++r) {
        float4 v = { z[4 * r + 0], z[4 * r + 1], z[4 * r + 2], z[4 * r + 3] };
        rp[r * 64 + lane] = v;
    }

    float acc = 0.0f;
#pragma unroll 1
    for (int rr = 0; rr < 4; ++rr) {               // rounds of 8 elems/lane
        int base = 0;
#pragma unroll
        for (int e = 0; e < 8; ++e) {
            const int r = rr * 2 + (e >> 2), jj = e & 3;
            const float pv = z[4 * r + jj];
            const unsigned long long mk = __ballot(pv > 0.0f);
            if (pv > 0.0f) {
                const int pos = base + lanes_below(mk);
                uint2 kp = { (unsigned)(r * 256 + lane * 4 + jj),
                             __builtin_bit_cast(unsigned, pv) };
                list[wave][pos] = kp;
            }
            base += __popcll(mk);
        }
        __threadfence_block();
        const int total = base;
        int i = 0;
        for (; i + 2 <= total; i += 2) {
            uint2 kp0 = list[wave][i], kp1 = list[wave][i + 1];
            float v0 = bf2f(Vh[(size_t)kp0.x * DMODEL + lane]);
            float v1 = bf2f(Vh[(size_t)kp1.x * DMODEL + lane]);
            acc += __builtin_bit_cast(float, kp0.y) * v0;
            acc += __builtin_bit_cast(float, kp1.y) * v1;
        }
        if (i < total) {
            uint2 kp0 = list[wave][i];
            acc += __builtin_bit_cast(float, kp0.y) * bf2f(Vh[(size_t)kp0.x * DMODEL + lane]);
        }
        __threadfence_block();
    }

    AO_bf[((size_t)(b_ * S_LEN + s)) * DMODEL + h * 64 + lane] = f2bf(acc);
}

// ---------------------- out = AO @ Wfc^T + bfc (bf16 A, fp32 W inline-cast)
__global__ __launch_bounds__(256)
void fc_gemm(const unsigned short* __restrict__ AO_bf,
             const float* __restrict__ Wfc,
             const float* __restrict__ bfc, float* __restrict__ out) {
    const int row0 = blockIdx.x * 128;
    const int col0 = blockIdx.y * 128;

    __shared__ unsigned short As[128 * 40];
    __shared__ unsigned short Bs[128 * 40];

    const int t = threadIdx.x;
    const int wid = t >> 6, lane = t & 63;
    const int wm = wid >> 1, wn = wid & 1;
    const int l = lane & 15, quad = lane >> 4;

    f32x4 acc[4][4];
#pragma unroll
    for (int i = 0; i < 4; ++i)
#pragma unroll
        for (int j = 0; j < 4; ++j) {
            float b_ = bfc[col0 + wn * 64 + j * 16 + l];
            acc[i][j] = (f32x4){ b_, b_, b_, b_ };
        }

    for (int k0 = 0; k0 < DMODEL; k0 += 32) {
        uint4 ar[2], br[2];
#pragma unroll
        for (int i = 0; i < 2; ++i) {
            const int c = t + i * 256, r = c >> 2, q = (c & 3) * 8;
            ar[i] = *(const uint4*)(AO_bf + (size_t)(row0 + r) * DMODEL + k0 + q);
            const float* wp = Wfc + (size_t)(col0 + r) * DMODEL + k0 + q;
            float4 w0 = *(const float4*)wp, w1 = *(const float4*)(wp + 4);
            br[i] = pack8(w0, w1);
        }
        __syncthreads();
#pragma unroll
        for (int i = 0; i < 2; ++i) {
            const int c = t + i * 256, r = c >> 2, q = (c & 3) * 8;
            *(uint4*)&As[r * 40 + q] = ar[i];
            *(uint4*)&Bs[r * 40 + q] = br[i];
        }
        __syncthreads();
        bf16x8 a[4], b[4];
#pragma unroll
        for (int i = 0; i < 4; ++i)
            a[i] = *(const bf16x8*)&As[(wm * 64 + i * 16 + l) * 40 + quad * 8];
#pragma unroll
        for (int j = 0; j < 4; ++j)
            b[j] = *(const bf16x8*)&Bs[(wn * 64 + j * 16 + l) * 40 + quad * 8];
#pragma unroll
        for (int i = 0; i < 4; ++i)
#pragma unroll
            for (int j = 0; j < 4; ++j)
                acc[i][j] = __builtin_amdgcn_mfma_f32_16x16x32_bf16(a[i], b[j], acc[i][j], 0, 0, 0);
    }

#pragma unroll
    for (int i = 0; i < 4; ++i)
#pragma unroll
        for (int r = 0; r < 4; ++r) {
            const int m = row0 + wm * 64 + i * 16 + quad * 4 + r;
#pragma unroll
            for (int j = 0; j < 4; ++j) {
                const int n = col0 + wn * 64 + j * 16 + l;
                out[(size_t)m * DMODEL + n] = acc[i][j][r];
            }
        }
}

// ----------------------------------------------------------------------- launch
extern "C" void kernel_launch(void* const* d_in, const int* in_sizes, int n_in,
                              void* d_out, int out_size, void* d_ws, size_t ws_size,
                              hipStream_t stream) {
    const float* q   = (const float*)d_in[0];
    const float* k   = (const float*)d_in[1];
    const float* v   = (const float*)d_in[2];
    const float* Wq  = (const float*)d_in[3];
    const float* bq  = (const float*)d_in[4];
    const float* Wk  = (const float*)d_in[5];
    const float* bk  = (const float*)d_in[6];
    const float* Wv  = (const float*)d_in[7];
    const float* bv  = (const float*)d_in[8];
    const float* Wfc = (const float*)d_in[9];
    const float* bfc = (const float*)d_in[10];

    float* out  = (float*)d_out;                       // [B,S,D] fp32
    float* attn = out + (size_t)M_ROWS * DMODEL;       // [B,H,S,S] fp32

    // workspace: Q_bf [0,8M), K_bf [8,16M), V_bf [16,24M), AO_bf [24,32M)
    char* ws = (char*)d_ws;
    unsigned short* Q_bf  = (unsigned short*)ws;
    unsigned short* K_bf  = (unsigned short*)(ws + (8u << 20));
    unsigned short* V_bf  = (unsigned short*)(ws + (16u << 20));
    unsigned short* AO_bf = (unsigned short*)(ws + (24u << 20));

    qkv_gemm<<<dim3(32, 8, 3), 256, 0, stream>>>(q, k, v, Wq, Wk, Wv,
                                                  bq, bk, bv, Q_bf, K_bf, V_bf);
    logits_gemm<<<dim3(16, 16, 32), 256, 0, stream>>>(Q_bf, K_bf, attn);
    smpv_kernel<<<16384, 256, 0, stream>>>(attn, V_bf, AO_bf);
    fc_gemm<<<dim3(32, 8), 256, 0, stream>>>(AO_bf, Wfc, bfc, out);
}